// Round 12
// baseline (437.019 us; speedup 1.0000x reference)
//
#include <hip/hip_runtime.h>
#include <math.h>

#define T_   4
#define B_   32
#define C_   512
#define N_   196
#define TB_  128
#define M_   25088          // TB_*N_
#define BNP_ 6272           // B_*N_  (t-plane stride in bn-space)
#define OUT1_ 12845056      // T_*B_*C_*N_

typedef unsigned short ushort_t;
typedef __attribute__((ext_vector_type(8)))  __bf16 bf16x8;
typedef __attribute__((ext_vector_type(16))) float  f32x16;

__device__ __forceinline__ ushort_t f2bf(float f) {
    unsigned int u = __float_as_uint(f);
    u = u + 0x7FFFu + ((u >> 16) & 1u);      // RN-even
    return (ushort_t)(u >> 16);
}
__device__ __forceinline__ float bf2f(ushort_t h) {
    return __uint_as_float(((unsigned int)h) << 16);
}

#define GL2LDS(gp, lp) \
    __builtin_amdgcn_global_load_lds((const __attribute__((address_space(1))) void*)(gp), \
                                     (__attribute__((address_space(3))) void*)(lp), 16, 0, 0)

// ---------------------------------------------------------------------------
// K0+K1 merged: blocks [0,3072) = prep; blocks [3072,4096) = lifx.
// (unchanged — passed rounds 7-11)
// ---------------------------------------------------------------------------
__global__ __launch_bounds__(256)
void prep_lifx_kernel(
    const float* __restrict__ qw, const float* __restrict__ kw,
    const float* __restrict__ vw, const float* __restrict__ ow,
    const float* __restrict__ qg, const float* __restrict__ qb, const float* __restrict__ qm, const float* __restrict__ qv,
    const float* __restrict__ kg, const float* __restrict__ kb, const float* __restrict__ km, const float* __restrict__ kvr,
    const float* __restrict__ vg, const float* __restrict__ vb, const float* __restrict__ vm, const float* __restrict__ vv,
    const float* __restrict__ og, const float* __restrict__ ob, const float* __restrict__ om, const float* __restrict__ ov,
    const float* __restrict__ obias,
    ushort_t* __restrict__ wsplit, ushort_t* __restrict__ osplit,
    float* __restrict__ scale_qkv, float* __restrict__ shift_qkv,
    float* __restrict__ scale_o,   float* __restrict__ shift_o,
    float* __restrict__ kvpart,
    const float* __restrict__ x, ushort_t* __restrict__ xs)
{
    __shared__ ushort_t tile[64 * 66];
    const int bid = blockIdx.x;
    const int tid = threadIdx.x;

    if (bid < 3072) {
        int i = bid * 256 + tid;                 // [0, 1536*512)
        int d = i >> 9, c = i & 511;
        const float* src = (d < 512) ? qw : (d < 1024) ? kw : vw;
        float wv = src[(d & 511) * 512 + c];
        ushort_t h = f2bf(wv);
        float r1 = wv - bf2f(h);
        ushort_t mm = f2bf(r1);
        wsplit[((size_t)d * 2 + 0) * 512 + c] = h;
        wsplit[((size_t)d * 2 + 1) * 512 + c] = mm;
        if (d < 512)
            osplit[(size_t)d * 512 + c] = f2bf(ow[d * 512 + c]);

        if (i < 3 * C_) {
            int p = i >> 9, dl = i & 511;
            const float* g = (p == 0) ? qg : (p == 1) ? kg : vg;
            const float* b = (p == 0) ? qb : (p == 1) ? kb : vb;
            const float* m = (p == 0) ? qm : (p == 1) ? km : vm;
            const float* r = (p == 0) ? qv : (p == 1) ? kvr : vv;
            float sc = g[dl] / sqrtf(r[dl] + 1e-5f);
            scale_qkv[i] = sc;
            shift_qkv[i] = b[dl] - m[dl] * sc;
        }
        if (i < C_) {
            float sc = og[i] / sqrtf(ov[i] + 1e-5f);
            scale_o[i] = sc;
            shift_o[i] = ob[i] - om[i] * sc + obias[i] * sc;
        }
        if (i < TB_ * C_) kvpart[i] = 0.f;
        return;
    }

    const int l = bid - 3072;                    // [0, 1024)
    const int n0 = (l & 3) * 64;
    const int c0 = ((l >> 2) & 7) * 64;
    const int b  = l >> 5;
    const int j = tid & 63, w = tid >> 6;
    const bool nok = (n0 + j) < N_;
    float v[16];
#pragma unroll
    for (int r = 0; r < 16; ++r) v[r] = 0.f;
    for (int t = 0; t < T_; ++t) {
        const float* xb = x + ((size_t)((t * B_ + b) * C_ + c0)) * N_ + n0 + j;
#pragma unroll
        for (int r = 0; r < 16; ++r) {
            int i = w * 16 + r;
            float xv = nok ? xb[(size_t)i * N_] : 0.f;
            v[r] = v[r] + (xv - v[r]) * 0.5f;
            bool s = (v[r] >= 1.0f);
            tile[j * 66 + i] = s ? 0x3F80 : 0;
            if (s) v[r] = 0.f;
        }
        __syncthreads();
#pragma unroll
        for (int p = 0; p < 2; ++p) {
            int w2 = tid + p * 256;
            int jj = w2 >> 3, ck = w2 & 7;
            if (n0 + jj < N_) {
                const unsigned int* src = reinterpret_cast<const unsigned int*>(&tile[jj * 66 + ck * 8]);
                uint4 dv; dv.x = src[0]; dv.y = src[1]; dv.z = src[2]; dv.w = src[3];
                size_t mp = (size_t)(b * N_ + n0 + jj) * 4 + t;      // permuted row
                *reinterpret_cast<uint4*>(&xs[mp * 512 + c0 + ck * 8]) = dv;
            }
        }
        __syncthreads();
    }
}

// ---------------------------------------------------------------------------
// K2 (round 12): qkv GEMM, occupancy-geometry experiment. Same proven
// 2-phase dbuf K-loop + ballot epilogue, re-tiled: 128m x 64d block,
// 256 thr / 4 waves (wave = 64m x 32d, acc[2][1] = 32 AGPR; ~96 total regs,
// __launch_bounds__(256,5) pins 5 waves/SIMD), LDS 32KB -> 5 blocks/CU
// = 20 waves/CU in 5 barrier groups (vs 16 in 2). Staging stays 4
// GL2LDS/wave/iter. Grid 4704 = 196 m_t x 24 d_t, m-major XCD swizzle
// (24 d_t siblings of an m_t run consecutively per XCD -> X tile L2-hot;
// W 3.1MB L2-resident per XCD).
// ---------------------------------------------------------------------------
__global__ __launch_bounds__(256, 5)
void qkv_gemm_lif(const ushort_t* __restrict__ W, const ushort_t* __restrict__ X,
                  const float* __restrict__ scale, const float* __restrict__ shift,
                  ushort_t* __restrict__ qspk, float* __restrict__ out2,
                  unsigned* __restrict__ kbit, unsigned* __restrict__ vbit)
{
    const int id = blockIdx.x;                   // [0, 4704)
    const int xw = id & 7, local = id >> 3;      // local in [0,588)
    const int ml = local / 24, d_t = local - ml * 24;
    const int m_t = ml * 8 + xw;
    if (m_t >= 196) return;
    const int m0 = m_t * 128;                    // m' base (128-tile)
    const int d0 = d_t * 64;                     // global d in [0,1536)

    // per buf: X 8 chunks of 1KB [mb(4)][ks(2)]; W 8 chunks [s(2)][db(2)][ks(2)]
    __shared__ ushort_t Xs[2][8 * 512];   // 16KB
    __shared__ ushort_t Ws[2][8 * 512];   // 16KB
    const int tid = threadIdx.x, wid = tid >> 6, lane = tid & 63;
    const int mw = (wid & 1) * 64, dw = (wid >> 1) * 32;
    const int row32 = lane & 31, khalf = lane >> 5;

    f32x16 acc[2] = {};                   // [i: m-block32] (single d-block32)

    // per tile each wave stages 4 chunks: X {wid, wid+4}, W {wid, wid+4}
    auto STAGE = [&](int buf, int k0) {
        {   int q = wid, mb = q >> 1, ks = q & 1;
            const ushort_t* g = X + (size_t)(m0 + mb * 32 + row32) * 512 + k0 + ks * 16 + khalf * 8;
            GL2LDS(g, &Xs[buf][q * 512]);
        }
        {   int q = wid + 4, mb = q >> 1, ks = q & 1;
            const ushort_t* g = X + (size_t)(m0 + mb * 32 + row32) * 512 + k0 + ks * 16 + khalf * 8;
            GL2LDS(g, &Xs[buf][q * 512]);
        }
        {   int q = wid, s = q >> 2, rem = q & 3, db = rem >> 1, ks = rem & 1;
            const ushort_t* g = W + ((size_t)(d0 + db * 32 + row32) * 2 + s) * 512 + k0 + ks * 16 + khalf * 8;
            GL2LDS(g, &Ws[buf][q * 512]);
        }
        {   int q = wid + 4, s = q >> 2, rem = q & 3, db = rem >> 1, ks = rem & 1;
            const ushort_t* g = W + ((size_t)(d0 + db * 32 + row32) * 2 + s) * 512 + k0 + ks * 16 + khalf * 8;
            GL2LDS(g, &Ws[buf][q * 512]);
        }
    };

    STAGE(0, 0);
    __syncthreads();
    int cur = 0;

    for (int it = 0; it < 16; ++it) {
        if (it < 15) STAGE(cur ^ 1, (it + 1) * 32);

        __builtin_amdgcn_s_setprio(1);
#pragma unroll
        for (int ks = 0; ks < 2; ++ks) {
            bf16x8 xfr[2];
#pragma unroll
            for (int i = 0; i < 2; ++i)
                xfr[i] = *reinterpret_cast<const bf16x8*>(
                    &Xs[cur][((((mw >> 5) + i) << 1) + ks) * 512 + lane * 8]);
#pragma unroll
            for (int s = 0; s < 2; ++s) {
                bf16x8 wfr = *reinterpret_cast<const bf16x8*>(
                    &Ws[cur][((s << 2) + ((dw >> 5) << 1) + ks) * 512 + lane * 8]);
#pragma unroll
                for (int i = 0; i < 2; ++i)
                    acc[i] = __builtin_amdgcn_mfma_f32_32x32x16_bf16(xfr[i], wfr, acc[i], 0, 0, 0);
            }
        }
        __builtin_amdgcn_s_setprio(0);
        __syncthreads();
        cur ^= 1;
    }

    // epilogue: BN -> LIF over t (reg&3). q: bf16 spike plane; k/v: ballot
    // bitmasks (proven r8-r11); v additionally writes out2 fp32.
    const int p = d0 >> 9;
    const bool isQ = (p == 0), isV = (p == 2);
    unsigned* __restrict__ bitp = (p == 1) ? kbit : vbit;
    {
        int d = d0 + dw + row32;
        float sc = scale[d], sh = shift[d];
        int dl = d & 511;
        int h = dl >> 6, hd = dl & 63;
        int cwi = ((d0 & 511) + dw) >> 5;        // uniform per wave: [0,16)
#pragma unroll
        for (int i = 0; i < 2; ++i) {
            int bnb = (m0 + mw + i * 32) >> 2;
            f32x16 a = acc[i];
#pragma unroll
            for (int g = 0; g < 4; ++g) {
                int bn = bnb + 2 * g + khalf;
                float p0 = fmaf(a[4 * g + 0], sc, sh);
                float p1 = fmaf(a[4 * g + 1], sc, sh);
                float p2 = fmaf(a[4 * g + 2], sc, sh);
                float p3 = fmaf(a[4 * g + 3], sc, sh);
                float v = p0 * 0.5f;
                bool s0 = (v >= 1.f); if (s0) v = 0.f;
                v = v + (p1 - v) * 0.5f;
                bool s1 = (v >= 1.f); if (s1) v = 0.f;
                v = v + (p2 - v) * 0.5f;
                bool s2 = (v >= 1.f); if (s2) v = 0.f;
                v = v + (p3 - v) * 0.5f;
                bool s3 = (v >= 1.f);

                if (isQ) {
                    ushort_t* b0 = qspk + (size_t)bn * 512 + dl;
                    b0[0]                      = s0 ? 0x3F80 : 0;
                    b0[(size_t)BNP_ * 512]     = s1 ? 0x3F80 : 0;
                    b0[(size_t)2 * BNP_ * 512] = s2 ? 0x3F80 : 0;
                    b0[(size_t)3 * BNP_ * 512] = s3 ? 0x3F80 : 0;
                } else {
                    const int bn_e = bnb + 2 * g;
                    bool sarr[4] = {s0, s1, s2, s3};
#pragma unroll
                    for (int t = 0; t < 4; ++t) {
                        unsigned long long bm = __ballot(sarr[t]);
                        if (lane == 0)
                            bitp[((size_t)t * BNP_ + bn_e) * 16 + cwi] = (unsigned)bm;
                        else if (lane == 32)
                            bitp[((size_t)t * BNP_ + bn_e + 1) * 16 + cwi] = (unsigned)(bm >> 32);
                    }
                    if (isV) {
                        int b = bn / N_, n = bn - b * N_;
                        float* o = out2 + (((size_t)b * 8 + h) * N_ + n) * 64 + hd;
                        o[0]                       = s0 ? 1.f : 0.f;
                        o[(size_t)1 * (OUT1_ / 4)] = s1 ? 1.f : 0.f;
                        o[(size_t)2 * (OUT1_ / 4)] = s2 ? 1.f : 0.f;
                        o[(size_t)3 * (OUT1_ / 4)] = s3 ? 1.f : 0.f;
                    }
                }
            }
        }
    }
}

// ---------------------------------------------------------------------------
// K3a: kv bit-count (unchanged — passed round 11; kv path now ~invisible)
// ---------------------------------------------------------------------------
__global__ __launch_bounds__(256)
void kv_count_kernel(const unsigned* __restrict__ kbit, const unsigned* __restrict__ vbit,
                     float* __restrict__ kvpart)
{
    __shared__ unsigned andw[98 * 16];           // 6.3 KB
    const int tid = threadIdx.x;
    const int tb = blockIdx.x >> 1, half = blockIdx.x & 1;
    const int t = tb >> 5, b = tb & 31;
    const size_t wbase = ((size_t)t * BNP_ + (size_t)b * N_ + half * 98) * 16;

    const uint4* k4 = reinterpret_cast<const uint4*>(kbit + wbase);
    const uint4* v4 = reinterpret_cast<const uint4*>(vbit + wbase);
    for (int w = tid; w < 392; w += 256) {       // 392 uint4 = 1568 words
        uint4 kq = k4[w], vq = v4[w];
        uint4 aq; aq.x = kq.x & vq.x; aq.y = kq.y & vq.y;
        aq.z = kq.z & vq.z; aq.w = kq.w & vq.w;
        *reinterpret_cast<uint4*>(&andw[w * 4]) = aq;
    }
    __syncthreads();

#pragma unroll
    for (int u = 0; u < 2; ++u) {
        int c = tid + u * 256;
        int cw = c >> 5, bit = c & 31;
        int cnt = 0;
        for (int r = 0; r < 98; ++r)             // broadcast LDS reads
            cnt += (int)((andw[r * 16 + cw] >> bit) & 1u);
        if (cnt) atomicAdd(&kvpart[tb * 512 + c], (float)cnt);
    }
}

// ---------------------------------------------------------------------------
// K4: LIF over t on kvpart -> kv spikes bf16 [tb][c] (unchanged)
// ---------------------------------------------------------------------------
__global__ void kv_lif_kernel(const float* __restrict__ kvpart, ushort_t* __restrict__ kvs)
{
    int i = blockIdx.x * 256 + threadIdx.x;      // 32*512
    if (i >= B_ * C_) return;
    int b = i >> 9, c = i & 511;
    float v = 0.f;
#pragma unroll
    for (int t = 0; t < T_; ++t) {
        float y = kvpart[((t * B_ + b) << 9) + c];
        v = v + (y - v) * 0.5f;
        bool s = (v >= 1.f);
        kvs[((t * B_ + b) << 9) + c] = s ? 0x3F80 : 0;
        if (s) v = 0.f;
    }
}

// ---------------------------------------------------------------------------
// K6: out GEMM with fused muly (unchanged — passed rounds 7-11).
// ---------------------------------------------------------------------------
__global__ __launch_bounds__(256)
void out_gemm(const ushort_t* __restrict__ A, const ushort_t* __restrict__ qs,
              const ushort_t* __restrict__ kvs,
              const float* __restrict__ scale, const float* __restrict__ shift,
              const float* __restrict__ xid, float* __restrict__ out)
{
    const int id = blockIdx.x;
    const int xw = id & 7, local = id >> 3;      // local < 100
    const int m_t = (local >> 2) * 8 + xw, d_t = local & 3;
    if (m_t >= 196) return;
    const int m0 = m_t * 128, d0 = d_t * 128;

    __shared__ ushort_t As[2][8 * 512];  // dbuf x [db(4)][ks(2)]
    __shared__ ushort_t Bs[2][8 * 512];  // dbuf x [mb(4)][ks(2)]
    const int tid = threadIdx.x, wid = tid >> 6, lane = tid & 63;
    const int dw = (wid >> 1) * 64, mw = (wid & 1) * 64;
    const int row32 = lane & 31, khalf = lane >> 5;

    int sm[2], stb[2], sq[2], sL[2];
#pragma unroll
    for (int u = 0; u < 2; ++u) {
        int s = tid + u * 256;
        sq[u] = s >> 6; sL[u] = s & 63;
        sm[u] = m0 + (sq[u] >> 1) * 32 + (sL[u] & 31);
        stb[u] = sm[u] / N_;
    }

    f32x16 acc[2][2] = {};               // [i: d-block32][j: m-block32]

    {
        uint4 o[2];
#pragma unroll
        for (int u = 0; u < 2; ++u) {
            int kk = (sq[u] & 1) * 16 + (sL[u] >> 5) * 8;
            uint4 qv = *reinterpret_cast<const uint4*>(&qs[(size_t)sm[u] * 512 + kk]);
            uint4 kv = *reinterpret_cast<const uint4*>(&kvs[(size_t)stb[u] * 512 + kk]);
            o[u].x = qv.x & kv.x; o[u].y = qv.y & kv.y;
            o[u].z = qv.z & kv.z; o[u].w = qv.w & kv.w;
        }
        for (int q = wid; q < 8; q += 4) {
            int db = q >> 1, ks2 = q & 1;
            const ushort_t* g = A + (size_t)(d0 + db * 32 + row32) * 512 + ks2 * 16 + khalf * 8;
            GL2LDS(g, &As[0][q * 512]);
        }
#pragma unroll
        for (int u = 0; u < 2; ++u)
            *reinterpret_cast<uint4*>(&Bs[0][sq[u] * 512 + sL[u] * 8]) = o[u];
    }
    __syncthreads();

    int buf = 0;
    for (int it = 0; it < 16; ++it) {
        uint4 nq[2], nk[2];
        if (it < 15) {
            int k0n = (it + 1) * 32;
#pragma unroll
            for (int u = 0; u < 2; ++u) {
                int kk = k0n + (sq[u] & 1) * 16 + (sL[u] >> 5) * 8;
                nq[u] = *reinterpret_cast<const uint4*>(&qs[(size_t)sm[u] * 512 + kk]);
                nk[u] = *reinterpret_cast<const uint4*>(&kvs[(size_t)stb[u] * 512 + kk]);
            }
            for (int q = wid; q < 8; q += 4) {
                int db = q >> 1, ks2 = q & 1;
                const ushort_t* g = A + (size_t)(d0 + db * 32 + row32) * 512 + k0n + ks2 * 16 + khalf * 8;
                GL2LDS(g, &As[buf ^ 1][q * 512]);
            }
        }

        __builtin_amdgcn_s_setprio(1);
#pragma unroll
        for (int ks = 0; ks < 2; ++ks) {
            bf16x8 afr[2];
#pragma unroll
            for (int i = 0; i < 2; ++i)
                afr[i] = *reinterpret_cast<const bf16x8*>(
                    &As[buf][(((dw >> 5) + i) * 2 + ks) * 512 + lane * 8]);
#pragma unroll
            for (int j = 0; j < 2; ++j) {
                bf16x8 bfr = *reinterpret_cast<const bf16x8*>(
                    &Bs[buf][(((mw >> 5) + j) * 2 + ks) * 512 + lane * 8]);
#pragma unroll
                for (int i = 0; i < 2; ++i)
                    acc[i][j] = __builtin_amdgcn_mfma_f32_32x32x16_bf16(afr[i], bfr, acc[i][j], 0, 0, 0);
            }
        }
        __builtin_amdgcn_s_setprio(0);

        if (it < 15) {
#pragma unroll
            for (int u = 0; u < 2; ++u) {
                uint4 o;
                o.x = nq[u].x & nk[u].x; o.y = nq[u].y & nk[u].y;
                o.z = nq[u].z & nk[u].z; o.w = nq[u].w & nk[u].w;
                *reinterpret_cast<uint4*>(&Bs[buf ^ 1][sq[u] * 512 + sL[u] * 8]) = o;
            }
        }
        __syncthreads();
        buf ^= 1;
    }

#pragma unroll
    for (int j = 0; j < 2; ++j) {
        int m = m0 + mw + j * 32 + row32;
        int tb = m / N_;
        int n  = m - tb * N_;
        size_t mbase = (size_t)tb * (C_ * N_) + n;
#pragma unroll
        for (int i = 0; i < 2; ++i) {
            int dbase = d0 + dw + i * 32 + 4 * khalf;
            f32x16 a = acc[i][j];
#pragma unroll
            for (int g = 0; g < 4; ++g) {
#pragma unroll
                for (int t = 0; t < 4; ++t) {
                    int d = dbase + t + 8 * g;
                    float val = fmaf(a[4 * g + t], scale[d], shift[d]);
                    size_t ad = mbase + (size_t)d * N_;
                    out[ad] = val + xid[ad];
                }
            }
        }
    }
}

// ---------------------------------------------------------------------------
extern "C" void kernel_launch(void* const* d_in, const int* in_sizes, int n_in,
                              void* d_out, int out_size, void* d_ws, size_t ws_size,
                              hipStream_t stream)
{
    const float* x    = (const float*)d_in[0];
    const float* q_w  = (const float*)d_in[1];
    const float* k_w  = (const float*)d_in[2];
    const float* v_w  = (const float*)d_in[3];
    const float* o_w  = (const float*)d_in[4];
    const float* o_b  = (const float*)d_in[5];
    const float* qg = (const float*)d_in[6],  *qb = (const float*)d_in[7],
               *qm = (const float*)d_in[8],  *qv = (const float*)d_in[9];
    const float* kg = (const float*)d_in[10], *kb = (const float*)d_in[11],
               *km = (const float*)d_in[12], *kv = (const float*)d_in[13];
    const float* vg = (const float*)d_in[14], *vb = (const float*)d_in[15],
               *vm = (const float*)d_in[16], *vv = (const float*)d_in[17];
    const float* og = (const float*)d_in[18], *ob = (const float*)d_in[19],
               *om = (const float*)d_in[20], *ov = (const float*)d_in[21];

    float* out1  = (float*)d_out;
    float* out2f = out1 + OUT1_;

    // d_ws layout (k/v plane regions reused for bitmasks, 1.6 MB each)
    ushort_t* spk    = (ushort_t*)d_ws;                      // q: [M][512] bf16 spikes
    ushort_t* xs     = spk + (size_t)3 * M_ * 512;           // [M][512] bf16 (m' order)
    ushort_t* wsplit = xs + (size_t)M_ * 512;                // 1536*2*512
    ushort_t* osplit = wsplit + (size_t)1536 * 2 * 512;      // 512*512
    float*    kvpart = (float*)(osplit + (size_t)512 * 512); // [TB][C]
    ushort_t* kvs    = (ushort_t*)(kvpart + TB_ * C_);       // [TB][C]
    float*    scq    = (float*)(kvs + TB_ * C_);
    float*    shq    = scq + 3 * C_;
    float*    sco    = shq + 3 * C_;
    float*    sho    = sco + C_;

    ushort_t* qsp = spk;
    unsigned* kbit = (unsigned*)(spk + (size_t)M_ * 512);        // in old k-plane
    unsigned* vbit = (unsigned*)(spk + (size_t)2 * M_ * 512);    // in old v-plane

    prep_lifx_kernel<<<4096, 256, 0, stream>>>(
        q_w, k_w, v_w, o_w,
        qg, qb, qm, qv, kg, kb, km, kv, vg, vb, vm, vv, og, ob, om, ov, o_b,
        wsplit, osplit, scq, shq, sco, sho, kvpart, x, xs);

    qkv_gemm_lif<<<4704, 256, 0, stream>>>(wsplit, xs, scq, shq, qsp, out2f, kbit, vbit);

    kv_count_kernel<<<256, 256, 0, stream>>>(kbit, vbit, kvpart);

    kv_lif_kernel<<<64, 256, 0, stream>>>(kvpart, kvs);

    out_gemm<<<800, 256, 0, stream>>>(osplit, qsp, kvs, sco, sho, x, out1);
}

// Round 13
// 413.704 us; speedup vs baseline: 1.0564x; 1.0564x over previous
//
#include <hip/hip_runtime.h>
#include <math.h>

#define T_   4
#define B_   32
#define C_   512
#define N_   196
#define TB_  128
#define M_   25088          // TB_*N_
#define BNP_ 6272           // B_*N_  (t-plane stride in bn-space)
#define OUT1_ 12845056      // T_*B_*C_*N_

typedef unsigned short ushort_t;
typedef __attribute__((ext_vector_type(8)))  __bf16 bf16x8;
typedef __attribute__((ext_vector_type(16))) float  f32x16;

__device__ __forceinline__ ushort_t f2bf(float f) {
    unsigned int u = __float_as_uint(f);
    u = u + 0x7FFFu + ((u >> 16) & 1u);      // RN-even
    return (ushort_t)(u >> 16);
}
__device__ __forceinline__ float bf2f(ushort_t h) {
    return __uint_as_float(((unsigned int)h) << 16);
}

#define GL2LDS(gp, lp) \
    __builtin_amdgcn_global_load_lds((const __attribute__((address_space(1))) void*)(gp), \
                                     (__attribute__((address_space(3))) void*)(lp), 16, 0, 0)

// ---------------------------------------------------------------------------
// K0+K1 merged: blocks [0,3072) = prep; blocks [3072,4096) = lifx.
// (unchanged — passed rounds 7-12)
// ---------------------------------------------------------------------------
__global__ __launch_bounds__(256)
void prep_lifx_kernel(
    const float* __restrict__ qw, const float* __restrict__ kw,
    const float* __restrict__ vw, const float* __restrict__ ow,
    const float* __restrict__ qg, const float* __restrict__ qb, const float* __restrict__ qm, const float* __restrict__ qv,
    const float* __restrict__ kg, const float* __restrict__ kb, const float* __restrict__ km, const float* __restrict__ kvr,
    const float* __restrict__ vg, const float* __restrict__ vb, const float* __restrict__ vm, const float* __restrict__ vv,
    const float* __restrict__ og, const float* __restrict__ ob, const float* __restrict__ om, const float* __restrict__ ov,
    const float* __restrict__ obias,
    ushort_t* __restrict__ wsplit, ushort_t* __restrict__ osplit,
    float* __restrict__ scale_qkv, float* __restrict__ shift_qkv,
    float* __restrict__ scale_o,   float* __restrict__ shift_o,
    float* __restrict__ kvpart,
    const float* __restrict__ x, ushort_t* __restrict__ xs)
{
    __shared__ ushort_t tile[64 * 66];
    const int bid = blockIdx.x;
    const int tid = threadIdx.x;

    if (bid < 3072) {
        int i = bid * 256 + tid;                 // [0, 1536*512)
        int d = i >> 9, c = i & 511;
        const float* src = (d < 512) ? qw : (d < 1024) ? kw : vw;
        float wv = src[(d & 511) * 512 + c];
        ushort_t h = f2bf(wv);
        float r1 = wv - bf2f(h);
        ushort_t mm = f2bf(r1);
        wsplit[((size_t)d * 2 + 0) * 512 + c] = h;
        wsplit[((size_t)d * 2 + 1) * 512 + c] = mm;
        if (d < 512)
            osplit[(size_t)d * 512 + c] = f2bf(ow[d * 512 + c]);

        if (i < 3 * C_) {
            int p = i >> 9, dl = i & 511;
            const float* g = (p == 0) ? qg : (p == 1) ? kg : vg;
            const float* b = (p == 0) ? qb : (p == 1) ? kb : vb;
            const float* m = (p == 0) ? qm : (p == 1) ? km : vm;
            const float* r = (p == 0) ? qv : (p == 1) ? kvr : vv;
            float sc = g[dl] / sqrtf(r[dl] + 1e-5f);
            scale_qkv[i] = sc;
            shift_qkv[i] = b[dl] - m[dl] * sc;
        }
        if (i < C_) {
            float sc = og[i] / sqrtf(ov[i] + 1e-5f);
            scale_o[i] = sc;
            shift_o[i] = ob[i] - om[i] * sc + obias[i] * sc;
        }
        if (i < TB_ * C_) kvpart[i] = 0.f;
        return;
    }

    const int l = bid - 3072;                    // [0, 1024)
    const int n0 = (l & 3) * 64;
    const int c0 = ((l >> 2) & 7) * 64;
    const int b  = l >> 5;
    const int j = tid & 63, w = tid >> 6;
    const bool nok = (n0 + j) < N_;
    float v[16];
#pragma unroll
    for (int r = 0; r < 16; ++r) v[r] = 0.f;
    for (int t = 0; t < T_; ++t) {
        const float* xb = x + ((size_t)((t * B_ + b) * C_ + c0)) * N_ + n0 + j;
#pragma unroll
        for (int r = 0; r < 16; ++r) {
            int i = w * 16 + r;
            float xv = nok ? xb[(size_t)i * N_] : 0.f;
            v[r] = v[r] + (xv - v[r]) * 0.5f;
            bool s = (v[r] >= 1.0f);
            tile[j * 66 + i] = s ? 0x3F80 : 0;
            if (s) v[r] = 0.f;
        }
        __syncthreads();
#pragma unroll
        for (int p = 0; p < 2; ++p) {
            int w2 = tid + p * 256;
            int jj = w2 >> 3, ck = w2 & 7;
            if (n0 + jj < N_) {
                const unsigned int* src = reinterpret_cast<const unsigned int*>(&tile[jj * 66 + ck * 8]);
                uint4 dv; dv.x = src[0]; dv.y = src[1]; dv.z = src[2]; dv.w = src[3];
                size_t mp = (size_t)(b * N_ + n0 + jj) * 4 + t;      // permuted row
                *reinterpret_cast<uint4*>(&xs[mp * 512 + c0 + ck * 8]) = dv;
            }
        }
        __syncthreads();
    }
}

// ---------------------------------------------------------------------------
// K2 (round 13): qkv GEMM — round-11 geometry verbatim (1200 blocks, 512
// thr, 256m x 128d, 2-phase dbuf, m-major XCD swizzle; round-12's 128x64
// re-tile regressed and is reverted). Epilogue: ALL THREE planes now emit
// 1-bit ballot bitmasks (the k/v path proven rounds 8-11, now also for q:
// q plane write 25.7MB -> 1.6MB); v additionally writes out2 fp32.
// ---------------------------------------------------------------------------
__global__ __launch_bounds__(512, 4)
void qkv_gemm_lif(const ushort_t* __restrict__ W, const ushort_t* __restrict__ X,
                  const float* __restrict__ scale, const float* __restrict__ shift,
                  float* __restrict__ out2,
                  unsigned* __restrict__ qbit, unsigned* __restrict__ kbit,
                  unsigned* __restrict__ vbit)
{
    const int id = blockIdx.x;
    const int xw = id & 7, local = id >> 3;      // local in [0,150)
    const int ml = local / 12, d_t = local - ml * 12;
    const int m_t = ml * 8 + xw;
    if (m_t >= 98) return;
    const int m0 = m_t * 256;                    // m' base (256-tile)
    const int d0 = d_t * 128;                    // global d in [0,1536)

    __shared__ ushort_t Xs[2][16 * 512];  // dbuf x 16 chunks of 1KB: [mb(8)][ks(2)]
    __shared__ ushort_t Ws[2][16 * 512];  // dbuf x 16 chunks: [s(2)][db(4)][ks(2)]
    const int tid = threadIdx.x, wid = tid >> 6, lane = tid & 63;
    const int mw = (wid & 3) * 64, dw = (wid >> 2) * 64;
    const int row32 = lane & 31, khalf = lane >> 5;

    f32x16 acc[2][2] = {};               // [i: m-block32][j: d-block32]

    auto STAGE = [&](int buf, int k0) {
        {   int q = wid, mb = q >> 1, ks = q & 1;
            const ushort_t* g = X + (size_t)(m0 + mb * 32 + row32) * 512 + k0 + ks * 16 + khalf * 8;
            GL2LDS(g, &Xs[buf][q * 512]);
        }
        {   int q = wid + 8, mb = q >> 1, ks = q & 1;
            const ushort_t* g = X + (size_t)(m0 + mb * 32 + row32) * 512 + k0 + ks * 16 + khalf * 8;
            GL2LDS(g, &Xs[buf][q * 512]);
        }
        {   int q = wid, s = q >> 3, rem = q & 7, db = rem >> 1, ks = rem & 1;
            const ushort_t* g = W + ((size_t)(d0 + db * 32 + row32) * 2 + s) * 512 + k0 + ks * 16 + khalf * 8;
            GL2LDS(g, &Ws[buf][q * 512]);
        }
        {   int q = wid + 8, s = q >> 3, rem = q & 7, db = rem >> 1, ks = rem & 1;
            const ushort_t* g = W + ((size_t)(d0 + db * 32 + row32) * 2 + s) * 512 + k0 + ks * 16 + khalf * 8;
            GL2LDS(g, &Ws[buf][q * 512]);
        }
    };

    STAGE(0, 0);
    __syncthreads();
    int cur = 0;

    for (int it = 0; it < 16; ++it) {
        if (it < 15) STAGE(cur ^ 1, (it + 1) * 32);

        __builtin_amdgcn_s_setprio(1);
#pragma unroll
        for (int ks = 0; ks < 2; ++ks) {
            bf16x8 xfr[2];
#pragma unroll
            for (int i = 0; i < 2; ++i)
                xfr[i] = *reinterpret_cast<const bf16x8*>(
                    &Xs[cur][(((mw >> 5) + i) * 2 + ks) * 512 + lane * 8]);
#pragma unroll
            for (int s = 0; s < 2; ++s)
#pragma unroll
                for (int j = 0; j < 2; ++j) {
                    bf16x8 wfr = *reinterpret_cast<const bf16x8*>(
                        &Ws[cur][(s * 8 + ((dw >> 5) + j) * 2 + ks) * 512 + lane * 8]);
#pragma unroll
                    for (int i = 0; i < 2; ++i)
                        acc[i][j] = __builtin_amdgcn_mfma_f32_32x32x16_bf16(xfr[i], wfr, acc[i][j], 0, 0, 0);
                }
        }
        __builtin_amdgcn_s_setprio(0);
        __syncthreads();
        cur ^= 1;
    }

    // epilogue: BN -> LIF over t (reg&3) -> ballot bitmask per plane
    // (word (t,bn,cw): bit (c&31) = spike of channel c); v also writes out2.
    const int p = d0 >> 9;
    const bool isV = (p == 2);
    unsigned* __restrict__ bitp = (p == 0) ? qbit : (p == 1) ? kbit : vbit;
#pragma unroll
    for (int j = 0; j < 2; ++j) {
        int d = d0 + dw + j * 32 + row32;
        float sc = scale[d], sh = shift[d];
        int dl = d & 511;
        int h = dl >> 6, hd = dl & 63;
        int cw = ((d0 & 511) + dw + j * 32) >> 5;    // uniform per wave: [0,16)
#pragma unroll
        for (int i = 0; i < 2; ++i) {
            int bnb = (m0 + mw + i * 32) >> 2;
            f32x16 a = acc[i][j];
#pragma unroll
            for (int g = 0; g < 4; ++g) {
                int bn = bnb + 2 * g + khalf;
                float p0 = fmaf(a[4 * g + 0], sc, sh);
                float p1 = fmaf(a[4 * g + 1], sc, sh);
                float p2 = fmaf(a[4 * g + 2], sc, sh);
                float p3 = fmaf(a[4 * g + 3], sc, sh);
                float v = p0 * 0.5f;
                bool s0 = (v >= 1.f); if (s0) v = 0.f;
                v = v + (p1 - v) * 0.5f;
                bool s1 = (v >= 1.f); if (s1) v = 0.f;
                v = v + (p2 - v) * 0.5f;
                bool s2 = (v >= 1.f); if (s2) v = 0.f;
                v = v + (p3 - v) * 0.5f;
                bool s3 = (v >= 1.f);

                const int bn_e = bnb + 2 * g;
                bool sarr[4] = {s0, s1, s2, s3};
#pragma unroll
                for (int t = 0; t < 4; ++t) {
                    unsigned long long bm = __ballot(sarr[t]);
                    if (lane == 0)
                        bitp[((size_t)t * BNP_ + bn_e) * 16 + cw] = (unsigned)bm;
                    else if (lane == 32)
                        bitp[((size_t)t * BNP_ + bn_e + 1) * 16 + cw] = (unsigned)(bm >> 32);
                }
                if (isV) {
                    int b = bn / N_, n = bn - b * N_;
                    float* o = out2 + (((size_t)b * 8 + h) * N_ + n) * 64 + hd;
                    o[0]                       = s0 ? 1.f : 0.f;
                    o[(size_t)1 * (OUT1_ / 4)] = s1 ? 1.f : 0.f;
                    o[(size_t)2 * (OUT1_ / 4)] = s2 ? 1.f : 0.f;
                    o[(size_t)3 * (OUT1_ / 4)] = s3 ? 1.f : 0.f;
                }
            }
        }
    }
}

// ---------------------------------------------------------------------------
// K3a: kv bit-count (unchanged — passed rounds 11-12)
// ---------------------------------------------------------------------------
__global__ __launch_bounds__(256)
void kv_count_kernel(const unsigned* __restrict__ kbit, const unsigned* __restrict__ vbit,
                     float* __restrict__ kvpart)
{
    __shared__ unsigned andw[98 * 16];           // 6.3 KB
    const int tid = threadIdx.x;
    const int tb = blockIdx.x >> 1, half = blockIdx.x & 1;
    const int t = tb >> 5, b = tb & 31;
    const size_t wbase = ((size_t)t * BNP_ + (size_t)b * N_ + half * 98) * 16;

    const uint4* k4 = reinterpret_cast<const uint4*>(kbit + wbase);
    const uint4* v4 = reinterpret_cast<const uint4*>(vbit + wbase);
    for (int w = tid; w < 392; w += 256) {       // 392 uint4 = 1568 words
        uint4 kq = k4[w], vq = v4[w];
        uint4 aq; aq.x = kq.x & vq.x; aq.y = kq.y & vq.y;
        aq.z = kq.z & vq.z; aq.w = kq.w & vq.w;
        *reinterpret_cast<uint4*>(&andw[w * 4]) = aq;
    }
    __syncthreads();

#pragma unroll
    for (int u = 0; u < 2; ++u) {
        int c = tid + u * 256;
        int cw = c >> 5, bit = c & 31;
        int cnt = 0;
        for (int r = 0; r < 98; ++r)             // broadcast LDS reads
            cnt += (int)((andw[r * 16 + cw] >> bit) & 1u);
        if (cnt) atomicAdd(&kvpart[tb * 512 + c], (float)cnt);
    }
}

// ---------------------------------------------------------------------------
// K4: LIF over t on kvpart -> kv spikes bf16 [tb][c] (unchanged)
// ---------------------------------------------------------------------------
__global__ void kv_lif_kernel(const float* __restrict__ kvpart, ushort_t* __restrict__ kvs)
{
    int i = blockIdx.x * 256 + threadIdx.x;      // 32*512
    if (i >= B_ * C_) return;
    int b = i >> 9, c = i & 511;
    float v = 0.f;
#pragma unroll
    for (int t = 0; t < T_; ++t) {
        float y = kvpart[((t * B_ + b) << 9) + c];
        v = v + (y - v) * 0.5f;
        bool s = (v >= 1.f);
        kvs[((t * B_ + b) << 9) + c] = s ? 0x3F80 : 0;
        if (s) v = 0.f;
    }
}

// ---------------------------------------------------------------------------
// K6: out GEMM — B-tile staged as expand(q-bit) & kvs. Round 13: q spikes
// arrive as a bitmask; per slot, one 4B word load + ~12 VALU replaces the
// 16B qs load (bit e of word (m,kk>>5) <-> channel kk+e; AND with kvs
// halves via 0xFFFF masks == 0x3F80&0x3F80 semantics). Rest unchanged.
// ---------------------------------------------------------------------------
__global__ __launch_bounds__(256)
void out_gemm(const ushort_t* __restrict__ A, const unsigned* __restrict__ qbit,
              const ushort_t* __restrict__ kvs,
              const float* __restrict__ scale, const float* __restrict__ shift,
              const float* __restrict__ xid, float* __restrict__ out)
{
    const int id = blockIdx.x;
    const int xw = id & 7, local = id >> 3;      // local < 100
    const int m_t = (local >> 2) * 8 + xw, d_t = local & 3;
    if (m_t >= 196) return;
    const int m0 = m_t * 128, d0 = d_t * 128;

    __shared__ ushort_t As[2][8 * 512];  // dbuf x [db(4)][ks(2)]
    __shared__ ushort_t Bs[2][8 * 512];  // dbuf x [mb(4)][ks(2)]
    const int tid = threadIdx.x, wid = tid >> 6, lane = tid & 63;
    const int dw = (wid >> 1) * 64, mw = (wid & 1) * 64;
    const int row32 = lane & 31, khalf = lane >> 5;

    int sm[2], stb[2], sq[2], sL[2];
#pragma unroll
    for (int u = 0; u < 2; ++u) {
        int s = tid + u * 256;
        sq[u] = s >> 6; sL[u] = s & 63;
        sm[u] = m0 + (sq[u] >> 1) * 32 + (sL[u] & 31);
        stb[u] = sm[u] / N_;
    }

    f32x16 acc[2][2] = {};               // [i: d-block32][j: m-block32]

    // expand 8 q-bits + kvs uint4 -> B fragment (q&kv of 0x3F80 patterns)
    auto EXPAND = [&](int u, int kk) -> uint4 {
        unsigned qw_ = qbit[(size_t)sm[u] * 16 + (kk >> 5)];
        unsigned q8 = (qw_ >> (kk & 31)) & 0xFFu;
        uint4 kv = *reinterpret_cast<const uint4*>(&kvs[(size_t)stb[u] * 512 + kk]);
        uint4 o;
        o.x = kv.x & (((q8 & 1u)   ? 0x0000FFFFu : 0u) | ((q8 & 2u)   ? 0xFFFF0000u : 0u));
        o.y = kv.y & (((q8 & 4u)   ? 0x0000FFFFu : 0u) | ((q8 & 8u)   ? 0xFFFF0000u : 0u));
        o.z = kv.z & (((q8 & 16u)  ? 0x0000FFFFu : 0u) | ((q8 & 32u)  ? 0xFFFF0000u : 0u));
        o.w = kv.w & (((q8 & 64u)  ? 0x0000FFFFu : 0u) | ((q8 & 128u) ? 0xFFFF0000u : 0u));
        return o;
    };

    // prologue: stage tile 0 into buf 0
    {
        uint4 o[2];
#pragma unroll
        for (int u = 0; u < 2; ++u) {
            int kk = (sq[u] & 1) * 16 + (sL[u] >> 5) * 8;
            o[u] = EXPAND(u, kk);
        }
        for (int q = wid; q < 8; q += 4) {
            int db = q >> 1, ks2 = q & 1;
            const ushort_t* g = A + (size_t)(d0 + db * 32 + row32) * 512 + ks2 * 16 + khalf * 8;
            GL2LDS(g, &As[0][q * 512]);
        }
#pragma unroll
        for (int u = 0; u < 2; ++u)
            *reinterpret_cast<uint4*>(&Bs[0][sq[u] * 512 + sL[u] * 8]) = o[u];
    }
    __syncthreads();

    int buf = 0;
    for (int it = 0; it < 16; ++it) {
        uint4 nb[2];
        if (it < 15) {
            int k0n = (it + 1) * 32;
#pragma unroll
            for (int u = 0; u < 2; ++u) {
                int kk = k0n + (sq[u] & 1) * 16 + (sL[u] >> 5) * 8;
                nb[u] = EXPAND(u, kk);
            }
            for (int q = wid; q < 8; q += 4) {
                int db = q >> 1, ks2 = q & 1;
                const ushort_t* g = A + (size_t)(d0 + db * 32 + row32) * 512 + k0n + ks2 * 16 + khalf * 8;
                GL2LDS(g, &As[buf ^ 1][q * 512]);
            }
        }

        __builtin_amdgcn_s_setprio(1);
#pragma unroll
        for (int ks = 0; ks < 2; ++ks) {
            bf16x8 afr[2];
#pragma unroll
            for (int i = 0; i < 2; ++i)
                afr[i] = *reinterpret_cast<const bf16x8*>(
                    &As[buf][(((dw >> 5) + i) * 2 + ks) * 512 + lane * 8]);
#pragma unroll
            for (int j = 0; j < 2; ++j) {
                bf16x8 bfr = *reinterpret_cast<const bf16x8*>(
                    &Bs[buf][(((mw >> 5) + j) * 2 + ks) * 512 + lane * 8]);
#pragma unroll
                for (int i = 0; i < 2; ++i)
                    acc[i][j] = __builtin_amdgcn_mfma_f32_32x32x16_bf16(afr[i], bfr, acc[i][j], 0, 0, 0);
            }
        }
        __builtin_amdgcn_s_setprio(0);

        if (it < 15) {
#pragma unroll
            for (int u = 0; u < 2; ++u)
                *reinterpret_cast<uint4*>(&Bs[buf ^ 1][sq[u] * 512 + sL[u] * 8]) = nb[u];
        }
        __syncthreads();      // drains vmcnt(0): A(t+1) landed; lgkm: Bs visible
        buf ^= 1;
    }

#pragma unroll
    for (int j = 0; j < 2; ++j) {
        int m = m0 + mw + j * 32 + row32;
        int tb = m / N_;
        int n  = m - tb * N_;
        size_t mbase = (size_t)tb * (C_ * N_) + n;
#pragma unroll
        for (int i = 0; i < 2; ++i) {
            int dbase = d0 + dw + i * 32 + 4 * khalf;
            f32x16 a = acc[i][j];
#pragma unroll
            for (int g = 0; g < 4; ++g) {
#pragma unroll
                for (int t = 0; t < 4; ++t) {
                    int d = dbase + t + 8 * g;
                    float val = fmaf(a[4 * g + t], scale[d], shift[d]);
                    size_t ad = mbase + (size_t)d * N_;
                    out[ad] = val + xid[ad];
                }
            }
        }
    }
}

// ---------------------------------------------------------------------------
extern "C" void kernel_launch(void* const* d_in, const int* in_sizes, int n_in,
                              void* d_out, int out_size, void* d_ws, size_t ws_size,
                              hipStream_t stream)
{
    const float* x    = (const float*)d_in[0];
    const float* q_w  = (const float*)d_in[1];
    const float* k_w  = (const float*)d_in[2];
    const float* v_w  = (const float*)d_in[3];
    const float* o_w  = (const float*)d_in[4];
    const float* o_b  = (const float*)d_in[5];
    const float* qg = (const float*)d_in[6],  *qb = (const float*)d_in[7],
               *qm = (const float*)d_in[8],  *qv = (const float*)d_in[9];
    const float* kg = (const float*)d_in[10], *kb = (const float*)d_in[11],
               *km = (const float*)d_in[12], *kv = (const float*)d_in[13];
    const float* vg = (const float*)d_in[14], *vb = (const float*)d_in[15],
               *vm = (const float*)d_in[16], *vv = (const float*)d_in[17];
    const float* og = (const float*)d_in[18], *ob = (const float*)d_in[19],
               *om = (const float*)d_in[20], *ov = (const float*)d_in[21];

    float* out1  = (float*)d_out;
    float* out2f = out1 + OUT1_;

    // d_ws layout (q/k/v plane regions reused for bitmasks, 1.6 MB each)
    ushort_t* spk    = (ushort_t*)d_ws;                      // bitmask region
    ushort_t* xs     = spk + (size_t)3 * M_ * 512;           // [M][512] bf16 (m' order)
    ushort_t* wsplit = xs + (size_t)M_ * 512;                // 1536*2*512
    ushort_t* osplit = wsplit + (size_t)1536 * 2 * 512;      // 512*512
    float*    kvpart = (float*)(osplit + (size_t)512 * 512); // [TB][C]
    ushort_t* kvs    = (ushort_t*)(kvpart + TB_ * C_);       // [TB][C]
    float*    scq    = (float*)(kvs + TB_ * C_);
    float*    shq    = scq + 3 * C_;
    float*    sco    = shq + 3 * C_;
    float*    sho    = sco + C_;

    unsigned* qbit = (unsigned*)spk;                             // old q-plane
    unsigned* kbit = (unsigned*)(spk + (size_t)M_ * 512);        // old k-plane
    unsigned* vbit = (unsigned*)(spk + (size_t)2 * M_ * 512);    // old v-plane

    prep_lifx_kernel<<<4096, 256, 0, stream>>>(
        q_w, k_w, v_w, o_w,
        qg, qb, qm, qv, kg, kb, km, kv, vg, vb, vm, vv, og, ob, om, ov, o_b,
        wsplit, osplit, scq, shq, sco, sho, kvpart, x, xs);

    qkv_gemm_lif<<<1200, 512, 0, stream>>>(wsplit, xs, scq, shq, out2f, qbit, kbit, vbit);

    kv_count_kernel<<<256, 256, 0, stream>>>(kbit, vbit, kvpart);

    kv_lif_kernel<<<64, 256, 0, stream>>>(kvpart, kvs);

    out_gemm<<<800, 256, 0, stream>>>(osplit, qbit, kvs, sco, sho, x, out1);
}

// Round 14
// 391.429 us; speedup vs baseline: 1.1165x; 1.0569x over previous
//
#include <hip/hip_runtime.h>
#include <math.h>

#define T_   4
#define B_   32
#define C_   512
#define N_   196
#define TB_  128
#define M_   25088          // TB_*N_
#define BNP_ 6272           // B_*N_  (t-plane stride in bn-space)
#define OUT1_ 12845056      // T_*B_*C_*N_

typedef unsigned short ushort_t;
typedef __attribute__((ext_vector_type(8)))  __bf16 bf16x8;
typedef __attribute__((ext_vector_type(16))) float  f32x16;

__device__ __forceinline__ ushort_t f2bf(float f) {
    unsigned int u = __float_as_uint(f);
    u = u + 0x7FFFu + ((u >> 16) & 1u);      // RN-even
    return (ushort_t)(u >> 16);
}
__device__ __forceinline__ float bf2f(ushort_t h) {
    return __uint_as_float(((unsigned int)h) << 16);
}

#define GL2LDS(gp, lp) \
    __builtin_amdgcn_global_load_lds((const __attribute__((address_space(1))) void*)(gp), \
                                     (__attribute__((address_space(3))) void*)(lp), 16, 0, 0)

// ---------------------------------------------------------------------------
// K0+K1 merged: blocks [0,3072) = prep; blocks [3072,4096) = lifx.
// (unchanged — passed rounds 7-13)
// ---------------------------------------------------------------------------
__global__ __launch_bounds__(256)
void prep_lifx_kernel(
    const float* __restrict__ qw, const float* __restrict__ kw,
    const float* __restrict__ vw, const float* __restrict__ ow,
    const float* __restrict__ qg, const float* __restrict__ qb, const float* __restrict__ qm, const float* __restrict__ qv,
    const float* __restrict__ kg, const float* __restrict__ kb, const float* __restrict__ km, const float* __restrict__ kvr,
    const float* __restrict__ vg, const float* __restrict__ vb, const float* __restrict__ vm, const float* __restrict__ vv,
    const float* __restrict__ og, const float* __restrict__ ob, const float* __restrict__ om, const float* __restrict__ ov,
    const float* __restrict__ obias,
    ushort_t* __restrict__ wsplit, ushort_t* __restrict__ osplit,
    float* __restrict__ scale_qkv, float* __restrict__ shift_qkv,
    float* __restrict__ scale_o,   float* __restrict__ shift_o,
    float* __restrict__ kvpart,
    const float* __restrict__ x, ushort_t* __restrict__ xs)
{
    __shared__ ushort_t tile[64 * 66];
    const int bid = blockIdx.x;
    const int tid = threadIdx.x;

    if (bid < 3072) {
        int i = bid * 256 + tid;                 // [0, 1536*512)
        int d = i >> 9, c = i & 511;
        const float* src = (d < 512) ? qw : (d < 1024) ? kw : vw;
        float wv = src[(d & 511) * 512 + c];
        ushort_t h = f2bf(wv);
        float r1 = wv - bf2f(h);
        ushort_t mm = f2bf(r1);
        wsplit[((size_t)d * 2 + 0) * 512 + c] = h;
        wsplit[((size_t)d * 2 + 1) * 512 + c] = mm;
        if (d < 512)
            osplit[(size_t)d * 512 + c] = f2bf(ow[d * 512 + c]);

        if (i < 3 * C_) {
            int p = i >> 9, dl = i & 511;
            const float* g = (p == 0) ? qg : (p == 1) ? kg : vg;
            const float* b = (p == 0) ? qb : (p == 1) ? kb : vb;
            const float* m = (p == 0) ? qm : (p == 1) ? km : vm;
            const float* r = (p == 0) ? qv : (p == 1) ? kvr : vv;
            float sc = g[dl] / sqrtf(r[dl] + 1e-5f);
            scale_qkv[i] = sc;
            shift_qkv[i] = b[dl] - m[dl] * sc;
        }
        if (i < C_) {
            float sc = og[i] / sqrtf(ov[i] + 1e-5f);
            scale_o[i] = sc;
            shift_o[i] = ob[i] - om[i] * sc + obias[i] * sc;
        }
        if (i < TB_ * C_) kvpart[i] = 0.f;
        return;
    }

    const int l = bid - 3072;                    // [0, 1024)
    const int n0 = (l & 3) * 64;
    const int c0 = ((l >> 2) & 7) * 64;
    const int b  = l >> 5;
    const int j = tid & 63, w = tid >> 6;
    const bool nok = (n0 + j) < N_;
    float v[16];
#pragma unroll
    for (int r = 0; r < 16; ++r) v[r] = 0.f;
    for (int t = 0; t < T_; ++t) {
        const float* xb = x + ((size_t)((t * B_ + b) * C_ + c0)) * N_ + n0 + j;
#pragma unroll
        for (int r = 0; r < 16; ++r) {
            int i = w * 16 + r;
            float xv = nok ? xb[(size_t)i * N_] : 0.f;
            v[r] = v[r] + (xv - v[r]) * 0.5f;
            bool s = (v[r] >= 1.0f);
            tile[j * 66 + i] = s ? 0x3F80 : 0;
            if (s) v[r] = 0.f;
        }
        __syncthreads();
#pragma unroll
        for (int p = 0; p < 2; ++p) {
            int w2 = tid + p * 256;
            int jj = w2 >> 3, ck = w2 & 7;
            if (n0 + jj < N_) {
                const unsigned int* src = reinterpret_cast<const unsigned int*>(&tile[jj * 66 + ck * 8]);
                uint4 dv; dv.x = src[0]; dv.y = src[1]; dv.z = src[2]; dv.w = src[3];
                size_t mp = (size_t)(b * N_ + n0 + jj) * 4 + t;      // permuted row
                *reinterpret_cast<uint4*>(&xs[mp * 512 + c0 + ck * 8]) = dv;
            }
        }
        __syncthreads();
    }
}

// ---------------------------------------------------------------------------
// K2: qkv GEMM — round-13 verbatim (passed, 126 µs, minimal writes).
// All three planes emit ballot bitmasks; v also writes out2 fp32.
// ---------------------------------------------------------------------------
__global__ __launch_bounds__(512, 4)
void qkv_gemm_lif(const ushort_t* __restrict__ W, const ushort_t* __restrict__ X,
                  const float* __restrict__ scale, const float* __restrict__ shift,
                  float* __restrict__ out2,
                  unsigned* __restrict__ qbit, unsigned* __restrict__ kbit,
                  unsigned* __restrict__ vbit)
{
    const int id = blockIdx.x;
    const int xw = id & 7, local = id >> 3;      // local in [0,150)
    const int ml = local / 12, d_t = local - ml * 12;
    const int m_t = ml * 8 + xw;
    if (m_t >= 98) return;
    const int m0 = m_t * 256;                    // m' base (256-tile)
    const int d0 = d_t * 128;                    // global d in [0,1536)

    __shared__ ushort_t Xs[2][16 * 512];  // dbuf x 16 chunks of 1KB: [mb(8)][ks(2)]
    __shared__ ushort_t Ws[2][16 * 512];  // dbuf x 16 chunks: [s(2)][db(4)][ks(2)]
    const int tid = threadIdx.x, wid = tid >> 6, lane = tid & 63;
    const int mw = (wid & 3) * 64, dw = (wid >> 2) * 64;
    const int row32 = lane & 31, khalf = lane >> 5;

    f32x16 acc[2][2] = {};               // [i: m-block32][j: d-block32]

    auto STAGE = [&](int buf, int k0) {
        {   int q = wid, mb = q >> 1, ks = q & 1;
            const ushort_t* g = X + (size_t)(m0 + mb * 32 + row32) * 512 + k0 + ks * 16 + khalf * 8;
            GL2LDS(g, &Xs[buf][q * 512]);
        }
        {   int q = wid + 8, mb = q >> 1, ks = q & 1;
            const ushort_t* g = X + (size_t)(m0 + mb * 32 + row32) * 512 + k0 + ks * 16 + khalf * 8;
            GL2LDS(g, &Xs[buf][q * 512]);
        }
        {   int q = wid, s = q >> 3, rem = q & 7, db = rem >> 1, ks = rem & 1;
            const ushort_t* g = W + ((size_t)(d0 + db * 32 + row32) * 2 + s) * 512 + k0 + ks * 16 + khalf * 8;
            GL2LDS(g, &Ws[buf][q * 512]);
        }
        {   int q = wid + 8, s = q >> 3, rem = q & 7, db = rem >> 1, ks = rem & 1;
            const ushort_t* g = W + ((size_t)(d0 + db * 32 + row32) * 2 + s) * 512 + k0 + ks * 16 + khalf * 8;
            GL2LDS(g, &Ws[buf][q * 512]);
        }
    };

    STAGE(0, 0);
    __syncthreads();
    int cur = 0;

    for (int it = 0; it < 16; ++it) {
        if (it < 15) STAGE(cur ^ 1, (it + 1) * 32);

        __builtin_amdgcn_s_setprio(1);
#pragma unroll
        for (int ks = 0; ks < 2; ++ks) {
            bf16x8 xfr[2];
#pragma unroll
            for (int i = 0; i < 2; ++i)
                xfr[i] = *reinterpret_cast<const bf16x8*>(
                    &Xs[cur][(((mw >> 5) + i) * 2 + ks) * 512 + lane * 8]);
#pragma unroll
            for (int s = 0; s < 2; ++s)
#pragma unroll
                for (int j = 0; j < 2; ++j) {
                    bf16x8 wfr = *reinterpret_cast<const bf16x8*>(
                        &Ws[cur][(s * 8 + ((dw >> 5) + j) * 2 + ks) * 512 + lane * 8]);
#pragma unroll
                    for (int i = 0; i < 2; ++i)
                        acc[i][j] = __builtin_amdgcn_mfma_f32_32x32x16_bf16(xfr[i], wfr, acc[i][j], 0, 0, 0);
                }
        }
        __builtin_amdgcn_s_setprio(0);
        __syncthreads();
        cur ^= 1;
    }

    // epilogue: BN -> LIF over t (reg&3) -> ballot bitmask per plane
    const int p = d0 >> 9;
    const bool isV = (p == 2);
    unsigned* __restrict__ bitp = (p == 0) ? qbit : (p == 1) ? kbit : vbit;
#pragma unroll
    for (int j = 0; j < 2; ++j) {
        int d = d0 + dw + j * 32 + row32;
        float sc = scale[d], sh = shift[d];
        int dl = d & 511;
        int h = dl >> 6, hd = dl & 63;
        int cw = ((d0 & 511) + dw + j * 32) >> 5;    // uniform per wave: [0,16)
#pragma unroll
        for (int i = 0; i < 2; ++i) {
            int bnb = (m0 + mw + i * 32) >> 2;
            f32x16 a = acc[i][j];
#pragma unroll
            for (int g = 0; g < 4; ++g) {
                int bn = bnb + 2 * g + khalf;
                float p0 = fmaf(a[4 * g + 0], sc, sh);
                float p1 = fmaf(a[4 * g + 1], sc, sh);
                float p2 = fmaf(a[4 * g + 2], sc, sh);
                float p3 = fmaf(a[4 * g + 3], sc, sh);
                float v = p0 * 0.5f;
                bool s0 = (v >= 1.f); if (s0) v = 0.f;
                v = v + (p1 - v) * 0.5f;
                bool s1 = (v >= 1.f); if (s1) v = 0.f;
                v = v + (p2 - v) * 0.5f;
                bool s2 = (v >= 1.f); if (s2) v = 0.f;
                v = v + (p3 - v) * 0.5f;
                bool s3 = (v >= 1.f);

                const int bn_e = bnb + 2 * g;
                bool sarr[4] = {s0, s1, s2, s3};
#pragma unroll
                for (int t = 0; t < 4; ++t) {
                    unsigned long long bm = __ballot(sarr[t]);
                    if (lane == 0)
                        bitp[((size_t)t * BNP_ + bn_e) * 16 + cw] = (unsigned)bm;
                    else if (lane == 32)
                        bitp[((size_t)t * BNP_ + bn_e + 1) * 16 + cw] = (unsigned)(bm >> 32);
                }
                if (isV) {
                    int b = bn / N_, n = bn - b * N_;
                    float* o = out2 + (((size_t)b * 8 + h) * N_ + n) * 64 + hd;
                    o[0]                       = s0 ? 1.f : 0.f;
                    o[(size_t)1 * (OUT1_ / 4)] = s1 ? 1.f : 0.f;
                    o[(size_t)2 * (OUT1_ / 4)] = s2 ? 1.f : 0.f;
                    o[(size_t)3 * (OUT1_ / 4)] = s3 ? 1.f : 0.f;
                }
            }
        }
    }
}

// ---------------------------------------------------------------------------
// K3a: kv bit-count (unchanged — passed rounds 11-13)
// ---------------------------------------------------------------------------
__global__ __launch_bounds__(256)
void kv_count_kernel(const unsigned* __restrict__ kbit, const unsigned* __restrict__ vbit,
                     float* __restrict__ kvpart)
{
    __shared__ unsigned andw[98 * 16];           // 6.3 KB
    const int tid = threadIdx.x;
    const int tb = blockIdx.x >> 1, half = blockIdx.x & 1;
    const int t = tb >> 5, b = tb & 31;
    const size_t wbase = ((size_t)t * BNP_ + (size_t)b * N_ + half * 98) * 16;

    const uint4* k4 = reinterpret_cast<const uint4*>(kbit + wbase);
    const uint4* v4 = reinterpret_cast<const uint4*>(vbit + wbase);
    for (int w = tid; w < 392; w += 256) {       // 392 uint4 = 1568 words
        uint4 kq = k4[w], vq = v4[w];
        uint4 aq; aq.x = kq.x & vq.x; aq.y = kq.y & vq.y;
        aq.z = kq.z & vq.z; aq.w = kq.w & vq.w;
        *reinterpret_cast<uint4*>(&andw[w * 4]) = aq;
    }
    __syncthreads();

#pragma unroll
    for (int u = 0; u < 2; ++u) {
        int c = tid + u * 256;
        int cw = c >> 5, bit = c & 31;
        int cnt = 0;
        for (int r = 0; r < 98; ++r)             // broadcast LDS reads
            cnt += (int)((andw[r * 16 + cw] >> bit) & 1u);
        if (cnt) atomicAdd(&kvpart[tb * 512 + c], (float)cnt);
    }
}

// ---------------------------------------------------------------------------
// K4 (round 14): LIF over t on kvpart -> kv spike BITMASK (ballot pattern
// proven r8-r13). bf16 kvs is dead (out_gemm now reads pre-ANDed muly).
// Wave lanes = 64 consecutive c for one b -> 1 ballot fills 2 words.
// ---------------------------------------------------------------------------
__global__ __launch_bounds__(256)
void kv_lif_kernel(const float* __restrict__ kvpart, unsigned* __restrict__ kvbits)
{
    int i = blockIdx.x * 256 + threadIdx.x;      // 32*512 = 16384 exact
    int b = i >> 9, c = i & 511;
    int lane = threadIdx.x & 63;
    float v = 0.f;
#pragma unroll
    for (int t = 0; t < T_; ++t) {
        float y = kvpart[((t * B_ + b) << 9) + c];
        v = v + (y - v) * 0.5f;
        bool s = (v >= 1.f);
        unsigned long long bm = __ballot(s);
        if (lane == 0)
            kvbits[(t * 32 + b) * 16 + (c >> 5)] = (unsigned)bm;
        else if (lane == 32)
            kvbits[(t * 32 + b) * 16 + (c >> 5)] = (unsigned)(bm >> 32);
        if (s) v = 0.f;
    }
}

// ---------------------------------------------------------------------------
// K5 (round 14): expand (qbit & kvbits) -> pre-ANDed bf16 B-plane muly
// [m(tb-major)][512]. One thread per 32-bit word: 2 word reads, expansion
// (t2*0x3F80 trick, carry-free), 64B coalesced store. Reuses the xs region
// (dead after qkv). 1568 blocks.
// ---------------------------------------------------------------------------
__global__ __launch_bounds__(256)
void expand_kernel(const unsigned* __restrict__ qbit, const unsigned* __restrict__ kvbits,
                   ushort_t* __restrict__ muly)
{
    int w = blockIdx.x * 256 + threadIdx.x;      // [0, 25088*16) exact
    int m = w >> 4, cw = w & 15;
    int tb = m / N_;                             // t*32+b (magic div)
    unsigned bits = qbit[w] & kvbits[tb * 16 + cw];
    uint4 o[4];
#pragma unroll
    for (int g = 0; g < 4; ++g) {
        unsigned e[4];
#pragma unroll
        for (int i2 = 0; i2 < 4; ++i2) {
            int p = g * 8 + i2 * 2;
            unsigned t2 = ((bits >> p) & 1u) | (((bits >> (p + 1)) & 1u) << 16);
            e[i2] = t2 * 0x3F80u;                // lo/hi bf16 1.0f patterns
        }
        o[g].x = e[0]; o[g].y = e[1]; o[g].z = e[2]; o[g].w = e[3];
    }
    uint4* dst = reinterpret_cast<uint4*>(muly + (size_t)m * 512 + cw * 32);
    dst[0] = o[0]; dst[1] = o[1]; dst[2] = o[2]; dst[3] = o[3];
}

// ---------------------------------------------------------------------------
// K6 (round 14): out GEMM — B staging is now pure GL2LDS from the
// pre-ANDed muly plane (identical structure to A staging / the proven qkv
// pipeline). No per-thread expansion, no kvs load, no reg round-trip.
// Epilogue: BN+bias + identity (unchanged).
// ---------------------------------------------------------------------------
__global__ __launch_bounds__(256)
void out_gemm(const ushort_t* __restrict__ A, const ushort_t* __restrict__ muly,
              const float* __restrict__ scale, const float* __restrict__ shift,
              const float* __restrict__ xid, float* __restrict__ out)
{
    const int id = blockIdx.x;
    const int xw = id & 7, local = id >> 3;      // local < 100
    const int m_t = (local >> 2) * 8 + xw, d_t = local & 3;
    if (m_t >= 196) return;
    const int m0 = m_t * 128, d0 = d_t * 128;

    __shared__ ushort_t As[2][8 * 512];  // dbuf x [db(4)][ks(2)]
    __shared__ ushort_t Bs[2][8 * 512];  // dbuf x [mb(4)][ks(2)]
    const int tid = threadIdx.x, wid = tid >> 6, lane = tid & 63;
    const int dw = (wid >> 1) * 64, mw = (wid & 1) * 64;
    const int row32 = lane & 31, khalf = lane >> 5;

    f32x16 acc[2][2] = {};               // [i: d-block32][j: m-block32]

    // stage one K-tile: each of 4 waves issues 2 A chunks + 2 B chunks
    auto STAGE = [&](int buf, int k0) {
        {   int q = wid, db = q >> 1, ks2 = q & 1;
            const ushort_t* g = A + (size_t)(d0 + db * 32 + row32) * 512 + k0 + ks2 * 16 + khalf * 8;
            GL2LDS(g, &As[buf][q * 512]);
        }
        {   int q = wid + 4, db = q >> 1, ks2 = q & 1;
            const ushort_t* g = A + (size_t)(d0 + db * 32 + row32) * 512 + k0 + ks2 * 16 + khalf * 8;
            GL2LDS(g, &As[buf][q * 512]);
        }
        {   int q = wid, mb = q >> 1, ks2 = q & 1;
            const ushort_t* g = muly + (size_t)(m0 + mb * 32 + row32) * 512 + k0 + ks2 * 16 + khalf * 8;
            GL2LDS(g, &Bs[buf][q * 512]);
        }
        {   int q = wid + 4, mb = q >> 1, ks2 = q & 1;
            const ushort_t* g = muly + (size_t)(m0 + mb * 32 + row32) * 512 + k0 + ks2 * 16 + khalf * 8;
            GL2LDS(g, &Bs[buf][q * 512]);
        }
    };

    STAGE(0, 0);
    __syncthreads();
    int buf = 0;

    for (int it = 0; it < 16; ++it) {
        if (it < 15) STAGE(buf ^ 1, (it + 1) * 32);

        __builtin_amdgcn_s_setprio(1);
#pragma unroll
        for (int ks = 0; ks < 2; ++ks) {
            bf16x8 afr[2];
#pragma unroll
            for (int i = 0; i < 2; ++i)
                afr[i] = *reinterpret_cast<const bf16x8*>(
                    &As[buf][(((dw >> 5) + i) * 2 + ks) * 512 + lane * 8]);
#pragma unroll
            for (int j = 0; j < 2; ++j) {
                bf16x8 bfr = *reinterpret_cast<const bf16x8*>(
                    &Bs[buf][(((mw >> 5) + j) * 2 + ks) * 512 + lane * 8]);
#pragma unroll
                for (int i = 0; i < 2; ++i)
                    acc[i][j] = __builtin_amdgcn_mfma_f32_32x32x16_bf16(afr[i], bfr, acc[i][j], 0, 0, 0);
            }
        }
        __builtin_amdgcn_s_setprio(0);
        __syncthreads();      // drains vmcnt(0): next tile landed; WAR on bufs
        buf ^= 1;
    }

#pragma unroll
    for (int j = 0; j < 2; ++j) {
        int m = m0 + mw + j * 32 + row32;
        int tb = m / N_;
        int n  = m - tb * N_;
        size_t mbase = (size_t)tb * (C_ * N_) + n;
#pragma unroll
        for (int i = 0; i < 2; ++i) {
            int dbase = d0 + dw + i * 32 + 4 * khalf;
            f32x16 a = acc[i][j];
#pragma unroll
            for (int g = 0; g < 4; ++g) {
#pragma unroll
                for (int t = 0; t < 4; ++t) {
                    int d = dbase + t + 8 * g;
                    float val = fmaf(a[4 * g + t], scale[d], shift[d]);
                    size_t ad = mbase + (size_t)d * N_;
                    out[ad] = val + xid[ad];
                }
            }
        }
    }
}

// ---------------------------------------------------------------------------
extern "C" void kernel_launch(void* const* d_in, const int* in_sizes, int n_in,
                              void* d_out, int out_size, void* d_ws, size_t ws_size,
                              hipStream_t stream)
{
    const float* x    = (const float*)d_in[0];
    const float* q_w  = (const float*)d_in[1];
    const float* k_w  = (const float*)d_in[2];
    const float* v_w  = (const float*)d_in[3];
    const float* o_w  = (const float*)d_in[4];
    const float* o_b  = (const float*)d_in[5];
    const float* qg = (const float*)d_in[6],  *qb = (const float*)d_in[7],
               *qm = (const float*)d_in[8],  *qv = (const float*)d_in[9];
    const float* kg = (const float*)d_in[10], *kb = (const float*)d_in[11],
               *km = (const float*)d_in[12], *kv = (const float*)d_in[13];
    const float* vg = (const float*)d_in[14], *vb = (const float*)d_in[15],
               *vm = (const float*)d_in[16], *vv = (const float*)d_in[17];
    const float* og = (const float*)d_in[18], *ob = (const float*)d_in[19],
               *om = (const float*)d_in[20], *ov = (const float*)d_in[21];

    float* out1  = (float*)d_out;
    float* out2f = out1 + OUT1_;

    // d_ws layout: q/k/v plane slots hold bitmasks (1.6 MB each);
    // xs region is reused as muly after qkv consumes it; kvs region
    // (dead bf16) reused for kvbits.
    ushort_t* spk    = (ushort_t*)d_ws;                      // bitmask region
    ushort_t* xs     = spk + (size_t)3 * M_ * 512;           // [M][512] bf16 (m' order) -> muly
    ushort_t* wsplit = xs + (size_t)M_ * 512;                // 1536*2*512
    ushort_t* osplit = wsplit + (size_t)1536 * 2 * 512;      // 512*512
    float*    kvpart = (float*)(osplit + (size_t)512 * 512); // [TB][C]
    ushort_t* kvs    = (ushort_t*)(kvpart + TB_ * C_);       // [TB][C] region -> kvbits
    float*    scq    = (float*)(kvs + TB_ * C_);
    float*    shq    = scq + 3 * C_;
    float*    sco    = shq + 3 * C_;
    float*    sho    = sco + C_;

    unsigned* qbit   = (unsigned*)spk;                           // old q-plane
    unsigned* kbit   = (unsigned*)(spk + (size_t)M_ * 512);      // old k-plane
    unsigned* vbit   = (unsigned*)(spk + (size_t)2 * M_ * 512);  // old v-plane
    unsigned* kvbits = (unsigned*)kvs;                           // 16 KB
    ushort_t* muly   = xs;                                       // reused post-qkv

    prep_lifx_kernel<<<4096, 256, 0, stream>>>(
        q_w, k_w, v_w, o_w,
        qg, qb, qm, qv, kg, kb, km, kv, vg, vb, vm, vv, og, ob, om, ov, o_b,
        wsplit, osplit, scq, shq, sco, sho, kvpart, x, xs);

    qkv_gemm_lif<<<1200, 512, 0, stream>>>(wsplit, xs, scq, shq, out2f, qbit, kbit, vbit);

    kv_count_kernel<<<256, 256, 0, stream>>>(kbit, vbit, kvpart);

    kv_lif_kernel<<<64, 256, 0, stream>>>(kvpart, kvbits);

    expand_kernel<<<1568, 256, 0, stream>>>(qbit, kvbits, muly);

    out_gemm<<<800, 256, 0, stream>>>(osplit, muly, sco, sho, x, out1);
}

// Round 16
// 390.889 us; speedup vs baseline: 1.1180x; 1.0014x over previous
//
#include <hip/hip_runtime.h>
#include <math.h>

#define T_   4
#define B_   32
#define C_   512
#define N_   196
#define TB_  128
#define M_   25088          // TB_*N_
#define BNP_ 6272           // B_*N_  (t-plane stride in bn-space)
#define OUT1_ 12845056      // T_*B_*C_*N_

typedef unsigned short ushort_t;
typedef __attribute__((ext_vector_type(8)))  __bf16 bf16x8;
typedef __attribute__((ext_vector_type(16))) float  f32x16;

__device__ __forceinline__ ushort_t f2bf(float f) {
    unsigned int u = __float_as_uint(f);
    u = u + 0x7FFFu + ((u >> 16) & 1u);      // RN-even
    return (ushort_t)(u >> 16);
}
__device__ __forceinline__ float bf2f(ushort_t h) {
    return __uint_as_float(((unsigned int)h) << 16);
}

#define GL2LDS(gp, lp) \
    __builtin_amdgcn_global_load_lds((const __attribute__((address_space(1))) void*)(gp), \
                                     (__attribute__((address_space(3))) void*)(lp), 16, 0, 0)

// ---------------------------------------------------------------------------
// K0+K1 merged: blocks [0,3072) = prep; blocks [3072,4096) = lifx.
// (unchanged — passed rounds 7-14)
// ---------------------------------------------------------------------------
__global__ __launch_bounds__(256)
void prep_lifx_kernel(
    const float* __restrict__ qw, const float* __restrict__ kw,
    const float* __restrict__ vw, const float* __restrict__ ow,
    const float* __restrict__ qg, const float* __restrict__ qb, const float* __restrict__ qm, const float* __restrict__ qv,
    const float* __restrict__ kg, const float* __restrict__ kb, const float* __restrict__ km, const float* __restrict__ kvr,
    const float* __restrict__ vg, const float* __restrict__ vb, const float* __restrict__ vm, const float* __restrict__ vv,
    const float* __restrict__ og, const float* __restrict__ ob, const float* __restrict__ om, const float* __restrict__ ov,
    const float* __restrict__ obias,
    ushort_t* __restrict__ wsplit, ushort_t* __restrict__ osplit,
    float* __restrict__ scale_qkv, float* __restrict__ shift_qkv,
    float* __restrict__ scale_o,   float* __restrict__ shift_o,
    float* __restrict__ kvpart,
    const float* __restrict__ x, ushort_t* __restrict__ xs)
{
    __shared__ ushort_t tile[64 * 66];
    const int bid = blockIdx.x;
    const int tid = threadIdx.x;

    if (bid < 3072) {
        int i = bid * 256 + tid;                 // [0, 1536*512)
        int d = i >> 9, c = i & 511;
        const float* src = (d < 512) ? qw : (d < 1024) ? kw : vw;
        float wv = src[(d & 511) * 512 + c];
        ushort_t h = f2bf(wv);
        float r1 = wv - bf2f(h);
        ushort_t mm = f2bf(r1);
        wsplit[((size_t)d * 2 + 0) * 512 + c] = h;
        wsplit[((size_t)d * 2 + 1) * 512 + c] = mm;
        if (d < 512)
            osplit[(size_t)d * 512 + c] = f2bf(ow[d * 512 + c]);

        if (i < 3 * C_) {
            int p = i >> 9, dl = i & 511;
            const float* g = (p == 0) ? qg : (p == 1) ? kg : vg;
            const float* b = (p == 0) ? qb : (p == 1) ? kb : vb;
            const float* m = (p == 0) ? qm : (p == 1) ? km : vm;
            const float* r = (p == 0) ? qv : (p == 1) ? kvr : vv;
            float sc = g[dl] / sqrtf(r[dl] + 1e-5f);
            scale_qkv[i] = sc;
            shift_qkv[i] = b[dl] - m[dl] * sc;
        }
        if (i < C_) {
            float sc = og[i] / sqrtf(ov[i] + 1e-5f);
            scale_o[i] = sc;
            shift_o[i] = ob[i] - om[i] * sc + obias[i] * sc;
        }
        if (i < TB_ * C_) kvpart[i] = 0.f;
        return;
    }

    const int l = bid - 3072;                    // [0, 1024)
    const int n0 = (l & 3) * 64;
    const int c0 = ((l >> 2) & 7) * 64;
    const int b  = l >> 5;
    const int j = tid & 63, w = tid >> 6;
    const bool nok = (n0 + j) < N_;
    float v[16];
#pragma unroll
    for (int r = 0; r < 16; ++r) v[r] = 0.f;
    for (int t = 0; t < T_; ++t) {
        const float* xb = x + ((size_t)((t * B_ + b) * C_ + c0)) * N_ + n0 + j;
#pragma unroll
        for (int r = 0; r < 16; ++r) {
            int i = w * 16 + r;
            float xv = nok ? xb[(size_t)i * N_] : 0.f;
            v[r] = v[r] + (xv - v[r]) * 0.5f;
            bool s = (v[r] >= 1.0f);
            tile[j * 66 + i] = s ? 0x3F80 : 0;
            if (s) v[r] = 0.f;
        }
        __syncthreads();
#pragma unroll
        for (int p = 0; p < 2; ++p) {
            int w2 = tid + p * 256;
            int jj = w2 >> 3, ck = w2 & 7;
            if (n0 + jj < N_) {
                const unsigned int* src = reinterpret_cast<const unsigned int*>(&tile[jj * 66 + ck * 8]);
                uint4 dv; dv.x = src[0]; dv.y = src[1]; dv.z = src[2]; dv.w = src[3];
                size_t mp = (size_t)(b * N_ + n0 + jj) * 4 + t;      // permuted row
                *reinterpret_cast<uint4*>(&xs[mp * 512 + c0 + ck * 8]) = dv;
            }
        }
        __syncthreads();
    }
}

// ---------------------------------------------------------------------------
// K2: qkv GEMM — round-14 verbatim (passed, 126 µs, minimal writes).
// All three planes emit ballot bitmasks; v also writes out2 fp32.
// ---------------------------------------------------------------------------
__global__ __launch_bounds__(512, 4)
void qkv_gemm_lif(const ushort_t* __restrict__ W, const ushort_t* __restrict__ X,
                  const float* __restrict__ scale, const float* __restrict__ shift,
                  float* __restrict__ out2,
                  unsigned* __restrict__ qbit, unsigned* __restrict__ kbit,
                  unsigned* __restrict__ vbit)
{
    const int id = blockIdx.x;
    const int xw = id & 7, local = id >> 3;      // local in [0,150)
    const int ml = local / 12, d_t = local - ml * 12;
    const int m_t = ml * 8 + xw;
    if (m_t >= 98) return;
    const int m0 = m_t * 256;                    // m' base (256-tile)
    const int d0 = d_t * 128;                    // global d in [0,1536)

    __shared__ ushort_t Xs[2][16 * 512];  // dbuf x 16 chunks of 1KB: [mb(8)][ks(2)]
    __shared__ ushort_t Ws[2][16 * 512];  // dbuf x 16 chunks: [s(2)][db(4)][ks(2)]
    const int tid = threadIdx.x, wid = tid >> 6, lane = tid & 63;
    const int mw = (wid & 3) * 64, dw = (wid >> 2) * 64;
    const int row32 = lane & 31, khalf = lane >> 5;

    f32x16 acc[2][2] = {};               // [i: m-block32][j: d-block32]

    auto STAGE = [&](int buf, int k0) {
        {   int q = wid, mb = q >> 1, ks = q & 1;
            const ushort_t* g = X + (size_t)(m0 + mb * 32 + row32) * 512 + k0 + ks * 16 + khalf * 8;
            GL2LDS(g, &Xs[buf][q * 512]);
        }
        {   int q = wid + 8, mb = q >> 1, ks = q & 1;
            const ushort_t* g = X + (size_t)(m0 + mb * 32 + row32) * 512 + k0 + ks * 16 + khalf * 8;
            GL2LDS(g, &Xs[buf][q * 512]);
        }
        {   int q = wid, s = q >> 3, rem = q & 7, db = rem >> 1, ks = rem & 1;
            const ushort_t* g = W + ((size_t)(d0 + db * 32 + row32) * 2 + s) * 512 + k0 + ks * 16 + khalf * 8;
            GL2LDS(g, &Ws[buf][q * 512]);
        }
        {   int q = wid + 8, s = q >> 3, rem = q & 7, db = rem >> 1, ks = rem & 1;
            const ushort_t* g = W + ((size_t)(d0 + db * 32 + row32) * 2 + s) * 512 + k0 + ks * 16 + khalf * 8;
            GL2LDS(g, &Ws[buf][q * 512]);
        }
    };

    STAGE(0, 0);
    __syncthreads();
    int cur = 0;

    for (int it = 0; it < 16; ++it) {
        if (it < 15) STAGE(cur ^ 1, (it + 1) * 32);

        __builtin_amdgcn_s_setprio(1);
#pragma unroll
        for (int ks = 0; ks < 2; ++ks) {
            bf16x8 xfr[2];
#pragma unroll
            for (int i = 0; i < 2; ++i)
                xfr[i] = *reinterpret_cast<const bf16x8*>(
                    &Xs[cur][(((mw >> 5) + i) * 2 + ks) * 512 + lane * 8]);
#pragma unroll
            for (int s = 0; s < 2; ++s)
#pragma unroll
                for (int j = 0; j < 2; ++j) {
                    bf16x8 wfr = *reinterpret_cast<const bf16x8*>(
                        &Ws[cur][(s * 8 + ((dw >> 5) + j) * 2 + ks) * 512 + lane * 8]);
#pragma unroll
                    for (int i = 0; i < 2; ++i)
                        acc[i][j] = __builtin_amdgcn_mfma_f32_32x32x16_bf16(xfr[i], wfr, acc[i][j], 0, 0, 0);
                }
        }
        __builtin_amdgcn_s_setprio(0);
        __syncthreads();
        cur ^= 1;
    }

    // epilogue: BN -> LIF over t (reg&3) -> ballot bitmask per plane
    // (word (t,bn,cw): bit (c&31) = spike of channel c); v also writes out2.
    const int p = d0 >> 9;
    const bool isV = (p == 2);
    unsigned* __restrict__ bitp = (p == 0) ? qbit : (p == 1) ? kbit : vbit;
#pragma unroll
    for (int j = 0; j < 2; ++j) {
        int d = d0 + dw + j * 32 + row32;
        float sc = scale[d], sh = shift[d];
        int dl = d & 511;
        int h = dl >> 6, hd = dl & 63;
        int cw = ((d0 & 511) + dw + j * 32) >> 5;    // uniform per wave: [0,16)
#pragma unroll
        for (int i = 0; i < 2; ++i) {
            int bnb = (m0 + mw + i * 32) >> 2;
            f32x16 a = acc[i][j];
#pragma unroll
            for (int g = 0; g < 4; ++g) {
                int bn = bnb + 2 * g + khalf;
                float p0 = fmaf(a[4 * g + 0], sc, sh);
                float p1 = fmaf(a[4 * g + 1], sc, sh);
                float p2 = fmaf(a[4 * g + 2], sc, sh);
                float p3 = fmaf(a[4 * g + 3], sc, sh);
                float v = p0 * 0.5f;
                bool s0 = (v >= 1.f); if (s0) v = 0.f;
                v = v + (p1 - v) * 0.5f;
                bool s1 = (v >= 1.f); if (s1) v = 0.f;
                v = v + (p2 - v) * 0.5f;
                bool s2 = (v >= 1.f); if (s2) v = 0.f;
                v = v + (p3 - v) * 0.5f;
                bool s3 = (v >= 1.f);

                const int bn_e = bnb + 2 * g;
                bool sarr[4] = {s0, s1, s2, s3};
#pragma unroll
                for (int t = 0; t < 4; ++t) {
                    unsigned long long bm = __ballot(sarr[t]);
                    if (lane == 0)
                        bitp[((size_t)t * BNP_ + bn_e) * 16 + cw] = (unsigned)bm;
                    else if (lane == 32)
                        bitp[((size_t)t * BNP_ + bn_e + 1) * 16 + cw] = (unsigned)(bm >> 32);
                }
                if (isV) {
                    int b = bn / N_, n = bn - b * N_;
                    float* o = out2 + (((size_t)b * 8 + h) * N_ + n) * 64 + hd;
                    o[0]                       = s0 ? 1.f : 0.f;
                    o[(size_t)1 * (OUT1_ / 4)] = s1 ? 1.f : 0.f;
                    o[(size_t)2 * (OUT1_ / 4)] = s2 ? 1.f : 0.f;
                    o[(size_t)3 * (OUT1_ / 4)] = s3 ? 1.f : 0.f;
                }
            }
        }
    }
}

// ---------------------------------------------------------------------------
// K3a: kv bit-count (unchanged — passed rounds 11-14)
// ---------------------------------------------------------------------------
__global__ __launch_bounds__(256)
void kv_count_kernel(const unsigned* __restrict__ kbit, const unsigned* __restrict__ vbit,
                     float* __restrict__ kvpart)
{
    __shared__ unsigned andw[98 * 16];           // 6.3 KB
    const int tid = threadIdx.x;
    const int tb = blockIdx.x >> 1, half = blockIdx.x & 1;
    const int t = tb >> 5, b = tb & 31;
    const size_t wbase = ((size_t)t * BNP_ + (size_t)b * N_ + half * 98) * 16;

    const uint4* k4 = reinterpret_cast<const uint4*>(kbit + wbase);
    const uint4* v4 = reinterpret_cast<const uint4*>(vbit + wbase);
    for (int w = tid; w < 392; w += 256) {       // 392 uint4 = 1568 words
        uint4 kq = k4[w], vq = v4[w];
        uint4 aq; aq.x = kq.x & vq.x; aq.y = kq.y & vq.y;
        aq.z = kq.z & vq.z; aq.w = kq.w & vq.w;
        *reinterpret_cast<uint4*>(&andw[w * 4]) = aq;
    }
    __syncthreads();

#pragma unroll
    for (int u = 0; u < 2; ++u) {
        int c = tid + u * 256;
        int cw = c >> 5, bit = c & 31;
        int cnt = 0;
        for (int r = 0; r < 98; ++r)             // broadcast LDS reads
            cnt += (int)((andw[r * 16 + cw] >> bit) & 1u);
        if (cnt) atomicAdd(&kvpart[tb * 512 + c], (float)cnt);
    }
}

// ---------------------------------------------------------------------------
// K4: LIF over t on kvpart -> kv spike BITMASK (ballot pattern proven
// r8-r13). bf16 kvs is dead (out_gemm reads pre-ANDed muly).
// ---------------------------------------------------------------------------
__global__ __launch_bounds__(256)
void kv_lif_kernel(const float* __restrict__ kvpart, unsigned* __restrict__ kvbits)
{
    int i = blockIdx.x * 256 + threadIdx.x;      // 32*512 = 16384 exact
    int b = i >> 9, c = i & 511;
    int lane = threadIdx.x & 63;
    float v = 0.f;
#pragma unroll
    for (int t = 0; t < T_; ++t) {
        float y = kvpart[((t * B_ + b) << 9) + c];
        v = v + (y - v) * 0.5f;
        bool s = (v >= 1.f);
        unsigned long long bm = __ballot(s);
        if (lane == 0)
            kvbits[(t * 32 + b) * 16 + (c >> 5)] = (unsigned)bm;
        else if (lane == 32)
            kvbits[(t * 32 + b) * 16 + (c >> 5)] = (unsigned)(bm >> 32);
        if (s) v = 0.f;
    }
}

// ---------------------------------------------------------------------------
// K5: expand (qbit & kvbits) -> pre-ANDed bf16 B-plane muly [m][512].
// One thread per 32-bit word: 2 word reads, t2*0x3F80 expansion, 64B
// coalesced store. Reuses the xs region (dead after qkv). 1568 blocks.
// (unchanged — passed round 14)
// ---------------------------------------------------------------------------
__global__ __launch_bounds__(256)
void expand_kernel(const unsigned* __restrict__ qbit, const unsigned* __restrict__ kvbits,
                   ushort_t* __restrict__ muly)
{
    int w = blockIdx.x * 256 + threadIdx.x;      // [0, 25088*16) exact
    int m = w >> 4, cw = w & 15;
    int tb = m / N_;                             // t*32+b (magic div)
    unsigned bits = qbit[w] & kvbits[tb * 16 + cw];
    uint4 o[4];
#pragma unroll
    for (int g = 0; g < 4; ++g) {
        unsigned e[4];
#pragma unroll
        for (int i2 = 0; i2 < 4; ++i2) {
            int p = g * 8 + i2 * 2;
            unsigned t2 = ((bits >> p) & 1u) | (((bits >> (p + 1)) & 1u) << 16);
            e[i2] = t2 * 0x3F80u;                // lo/hi bf16 1.0f patterns
        }
        o[g].x = e[0]; o[g].y = e[1]; o[g].z = e[2]; o[g].w = e[3];
    }
    uint4* dst = reinterpret_cast<uint4*>(muly + (size_t)m * 512 + cw * 32);
    dst[0] = o[0]; dst[1] = o[1]; dst[2] = o[2]; dst[3] = o[3];
}

// ---------------------------------------------------------------------------
// K6: out GEMM — B staging is pure GL2LDS from the pre-ANDed muly plane
// (identical structure to A staging). Epilogue: BN+bias + identity.
// (unchanged — passed round 14)
// ---------------------------------------------------------------------------
__global__ __launch_bounds__(256)
void out_gemm(const ushort_t* __restrict__ A, const ushort_t* __restrict__ muly,
              const float* __restrict__ scale, const float* __restrict__ shift,
              const float* __restrict__ xid, float* __restrict__ out)
{
    const int id = blockIdx.x;
    const int xw = id & 7, local = id >> 3;      // local < 100
    const int m_t = (local >> 2) * 8 + xw, d_t = local & 3;
    if (m_t >= 196) return;
    const int m0 = m_t * 128, d0 = d_t * 128;

    __shared__ ushort_t As[2][8 * 512];  // dbuf x [db(4)][ks(2)]
    __shared__ ushort_t Bs[2][8 * 512];  // dbuf x [mb(4)][ks(2)]
    const int tid = threadIdx.x, wid = tid >> 6, lane = tid & 63;
    const int dw = (wid >> 1) * 64, mw = (wid & 1) * 64;
    const int row32 = lane & 31, khalf = lane >> 5;

    f32x16 acc[2][2] = {};               // [i: d-block32][j: m-block32]

    // stage one K-tile: each of 4 waves issues 2 A chunks + 2 B chunks
    auto STAGE = [&](int buf, int k0) {
        {   int q = wid, db = q >> 1, ks2 = q & 1;
            const ushort_t* g = A + (size_t)(d0 + db * 32 + row32) * 512 + k0 + ks2 * 16 + khalf * 8;
            GL2LDS(g, &As[buf][q * 512]);
        }
        {   int q = wid + 4, db = q >> 1, ks2 = q & 1;
            const ushort_t* g = A + (size_t)(d0 + db * 32 + row32) * 512 + k0 + ks2 * 16 + khalf * 8;
            GL2LDS(g, &As[buf][q * 512]);
        }
        {   int q = wid, mb = q >> 1, ks2 = q & 1;
            const ushort_t* g = muly + (size_t)(m0 + mb * 32 + row32) * 512 + k0 + ks2 * 16 + khalf * 8;
            GL2LDS(g, &Bs[buf][q * 512]);
        }
        {   int q = wid + 4, mb = q >> 1, ks2 = q & 1;
            const ushort_t* g = muly + (size_t)(m0 + mb * 32 + row32) * 512 + k0 + ks2 * 16 + khalf * 8;
            GL2LDS(g, &Bs[buf][q * 512]);
        }
    };

    STAGE(0, 0);
    __syncthreads();
    int buf = 0;

    for (int it = 0; it < 16; ++it) {
        if (it < 15) STAGE(buf ^ 1, (it + 1) * 32);

        __builtin_amdgcn_s_setprio(1);
#pragma unroll
        for (int ks = 0; ks < 2; ++ks) {
            bf16x8 afr[2];
#pragma unroll
            for (int i = 0; i < 2; ++i)
                afr[i] = *reinterpret_cast<const bf16x8*>(
                    &As[buf][(((dw >> 5) + i) * 2 + ks) * 512 + lane * 8]);
#pragma unroll
            for (int j = 0; j < 2; ++j) {
                bf16x8 bfr = *reinterpret_cast<const bf16x8*>(
                    &Bs[buf][(((mw >> 5) + j) * 2 + ks) * 512 + lane * 8]);
#pragma unroll
                for (int i = 0; i < 2; ++i)
                    acc[i][j] = __builtin_amdgcn_mfma_f32_32x32x16_bf16(afr[i], bfr, acc[i][j], 0, 0, 0);
            }
        }
        __builtin_amdgcn_s_setprio(0);
        __syncthreads();      // drains vmcnt(0): next tile landed; WAR on bufs
        buf ^= 1;
    }

#pragma unroll
    for (int j = 0; j < 2; ++j) {
        int m = m0 + mw + j * 32 + row32;
        int tb = m / N_;
        int n  = m - tb * N_;
        size_t mbase = (size_t)tb * (C_ * N_) + n;
#pragma unroll
        for (int i = 0; i < 2; ++i) {
            int dbase = d0 + dw + i * 32 + 4 * khalf;
            f32x16 a = acc[i][j];
#pragma unroll
            for (int g = 0; g < 4; ++g) {
#pragma unroll
                for (int t = 0; t < 4; ++t) {
                    int d = dbase + t + 8 * g;
                    float val = fmaf(a[4 * g + t], scale[d], shift[d]);
                    size_t ad = mbase + (size_t)d * N_;
                    out[ad] = val + xid[ad];
                }
            }
        }
    }
}

// ---------------------------------------------------------------------------
extern "C" void kernel_launch(void* const* d_in, const int* in_sizes, int n_in,
                              void* d_out, int out_size, void* d_ws, size_t ws_size,
                              hipStream_t stream)
{
    const float* x    = (const float*)d_in[0];
    const float* q_w  = (const float*)d_in[1];
    const float* k_w  = (const float*)d_in[2];
    const float* v_w  = (const float*)d_in[3];
    const float* o_w  = (const float*)d_in[4];
    const float* o_b  = (const float*)d_in[5];
    const float* qg = (const float*)d_in[6],  *qb = (const float*)d_in[7],
               *qm = (const float*)d_in[8],  *qv = (const float*)d_in[9];
    const float* kg = (const float*)d_in[10], *kb = (const float*)d_in[11],
               *km = (const float*)d_in[12], *kv = (const float*)d_in[13];
    const float* vg = (const float*)d_in[14], *vb = (const float*)d_in[15],
               *vm = (const float*)d_in[16], *vv = (const float*)d_in[17];
    const float* og = (const float*)d_in[18], *ob = (const float*)d_in[19],
               *om = (const float*)d_in[20], *ov = (const float*)d_in[21];

    float* out1  = (float*)d_out;
    float* out2f = out1 + OUT1_;

    // d_ws layout: q/k/v plane slots hold bitmasks (1.6 MB each);
    // xs region reused as muly after qkv consumes it; kvs region -> kvbits.
    ushort_t* spk    = (ushort_t*)d_ws;                      // bitmask region
    ushort_t* xs     = spk + (size_t)3 * M_ * 512;           // [M][512] bf16 (m' order) -> muly
    ushort_t* wsplit = xs + (size_t)M_ * 512;                // 1536*2*512
    ushort_t* osplit = wsplit + (size_t)1536 * 2 * 512;      // 512*512
    float*    kvpart = (float*)(osplit + (size_t)512 * 512); // [TB][C]
    ushort_t* kvs    = (ushort_t*)(kvpart + TB_ * C_);       // [TB][C] region -> kvbits
    float*    scq    = (float*)(kvs + TB_ * C_);
    float*    shq    = scq + 3 * C_;
    float*    sco    = shq + 3 * C_;
    float*    sho    = sco + C_;

    unsigned* qbit   = (unsigned*)spk;                           // old q-plane
    unsigned* kbit   = (unsigned*)(spk + (size_t)M_ * 512);      // old k-plane
    unsigned* vbit   = (unsigned*)(spk + (size_t)2 * M_ * 512);  // old v-plane
    unsigned* kvbits = (unsigned*)kvs;                           // 8 KB
    ushort_t* muly   = xs;                                       // reused post-qkv

    prep_lifx_kernel<<<4096, 256, 0, stream>>>(
        q_w, k_w, v_w, o_w,
        qg, qb, qm, qv, kg, kb, km, kv, vg, vb, vm, vv, og, ob, om, ov, o_b,
        wsplit, osplit, scq, shq, sco, sho, kvpart, x, xs);

    qkv_gemm_lif<<<1200, 512, 0, stream>>>(wsplit, xs, scq, shq, out2f, qbit, kbit, vbit);

    kv_count_kernel<<<256, 256, 0, stream>>>(kbit, vbit, kvpart);

    kv_lif_kernel<<<64, 256, 0, stream>>>(kvpart, kvbits);

    expand_kernel<<<1568, 256, 0, stream>>>(qbit, kvbits, muly);

    out_gemm<<<800, 256, 0, stream>>>(osplit, muly, sco, sho, x, out1);
}